// Round 1
// 337.625 us; speedup vs baseline: 1.1537x; 1.1537x over previous
//
#include <hip/hip_runtime.h>
#include <hip/hip_bf16.h>

// BandSplit on MI355X — round 2.
// R1 post-mortem: all our kernels < 157 us (fills dominate top-5). Model:
// main_kernel is latency-bound (17 serial phase-1 load round-trips between
// barriers, 2 blocks/CU from 63.5 KB LDS). This round: batch phase-1 loads
// (4-wide), shrink LDS to 33 KB via two half-stage output passes -> 4
// blocks/CU with __launch_bounds__(256,4), fuse stats+wprep into one launch.
//
// ws layout (f32 unless noted):
//   sA : float[16][1024]    rsigma*gn_w at K-padded positions (band i -> kp=32i)
//   sB : float[16][1024]    gn_b - mu*rsigma*gn_w
//   wf : ushort[32*8*64*8]  fc_w as bf16 in MFMA B-fragment order, zero padded
// total 393,216 B (unchanged).

typedef short short8 __attribute__((ext_vector_type(8)));
typedef float floatx4 __attribute__((ext_vector_type(4)));

__device__ __forceinline__ unsigned short f2bf(float f) {
  unsigned int u = __float_as_uint(f);
  u = (u + 0x7fffu + ((u >> 16) & 1u)) >> 16;  // RNE
  return (unsigned short)u;
}

// BANDS = [2, 3x10, 8x12, 16x7, 17]; c = 2*band; K padded to 32 per band
// (band 30: c=34 -> ksteps 30 and 31).
__device__ __forceinline__ int band_of_f(int f) {
  if (f < 2) return 0;
  if (f < 32) return 1 + (f - 2) / 3;
  if (f < 128) return 11 + (f - 32) / 8;
  if (f < 240) return 23 + (f - 128) / 16;
  return 30;
}
__device__ __forceinline__ int f0_of_band(int i) {
  if (i == 0) return 0;
  if (i <= 10) return 2 + 3 * (i - 1);
  if (i <= 22) return 32 + 8 * (i - 11);
  if (i <= 29) return 128 + 16 * (i - 23);
  return 240;
}
__device__ __forceinline__ int c_of_band(int i) {
  if (i == 0) return 4;
  if (i <= 10) return 6;
  if (i <= 22) return 16;
  if (i <= 29) return 32;
  return 34;
}
__device__ __forceinline__ int bw_of_band(int i) {
  if (i == 0) return 2;
  if (i <= 10) return 3;
  if (i <= 22) return 8;
  if (i <= 29) return 16;
  return 17;
}

// ---------------------------------------------------------------------------
// Kernel 1 (fused): blocks 0..495 = per-(band,batch) GroupNorm stats folded
// into per-channel affine sA/sB; blocks 496..559 = fc_w (f32) -> bf16 MFMA
// B-fragment order. Independent work, one launch.
// ---------------------------------------------------------------------------
__global__ __launch_bounds__(256) void prep_kernel(
    const float* __restrict__ x,
    const float* __restrict__ gn_w,
    const float* __restrict__ gn_b,
    const float* __restrict__ fc_w,
    float* __restrict__ sA, float* __restrict__ sB,
    unsigned short* __restrict__ wf) {
  const int blk = blockIdx.x;
  const int tid = threadIdx.x;
  __shared__ float redS[4], redQ[4];
  __shared__ float musig[2];

  if (blk >= 496) {
    // ---- wprep part: flat short8 index gid = ks*512 + ot*64 + lane;
    // element j = Wp[kp = ks*32 + (lane>>4)*8 + j][o = ot*16 + (lane&15)].
    const int gid = (blk - 496) * 256 + tid;  // 0..16383
    const int ks = gid >> 9;
    const int rem = gid & 511;
    const int ot = rem >> 6;
    const int l = rem & 63;
    const int o = ot * 16 + (l & 15);
    const int kbase = ks * 32 + ((l >> 4) << 3);
    short8 v;
#pragma unroll
    for (int j = 0; j < 8; ++j) {
      int kp = kbase + j;
      int i = (kp >= 960) ? 30 : (kp >> 5);
      int cidx = kp - (i << 5);
      int c = c_of_band(i);
      unsigned short w =
          (cidx < c) ? f2bf(fc_w[(i * 128 + o) * 34 + cidx]) : (unsigned short)0;
      v[j] = (short)w;
    }
    ((short8*)wf)[gid] = v;
    return;
  }

  // ---- stats part
  const int i = blk % 31;  // band
  const int b = blk / 31;  // batch
  const int bw = bw_of_band(i);
  const int f0 = f0_of_band(i);
  // slab: x[b, f0:f0+bw, :, :] -> contiguous bw*2000 f32; start*4 % 16 == 0
  const long start = ((long)(b * 257 + f0)) * 2000;
  const float4* p4 = (const float4*)(x + start);
  const int nchunk = bw * 500;  // 4 f32 per chunk

  float s = 0.f, sq = 0.f;
  for (int e = tid; e < nchunk; e += 256) {
    float4 v = p4[e];
    s += v.x + v.y + v.z + v.w;
    sq += v.x * v.x + v.y * v.y + v.z * v.z + v.w * v.w;
  }
#pragma unroll
  for (int off = 32; off > 0; off >>= 1) {
    s += __shfl_down(s, off);
    sq += __shfl_down(sq, off);
  }
  if ((tid & 63) == 0) { redS[tid >> 6] = s; redQ[tid >> 6] = sq; }
  __syncthreads();
  if (tid == 0) {
    float S = redS[0] + redS[1] + redS[2] + redS[3];
    float Q = redQ[0] + redQ[1] + redQ[2] + redQ[3];
    float cnt = (float)(bw * 2000);
    float mu = S / cnt;
    float var = Q / cnt - mu * mu;
    musig[0] = mu;
    musig[1] = rsqrtf(var + 1e-5f);
  }
  __syncthreads();
  const int c = c_of_band(i);
  if (tid < c) {
    float mu = musig[0], rs = musig[1];
    float gw = gn_w[i * 34 + tid];
    float gb = gn_b[i * 34 + tid];
    float a = rs * gw;
    int kp = i * 32 + tid;  // band 30 spills into kstep 31
    sA[(b << 10) + kp] = a;
    sB[(b << 10) + kp] = gb - mu * a;
  }
}

// ---------------------------------------------------------------------------
// Kernel 2: main. Block = (o-quarter 32, t-tile 16, batch); q is the fastest
// grid dim so the 4 blocks sharing an x-slice are dispatch-adjacent.
// Phase 1: stage normalized bf16 xn in A-fragment layout (LDS), loads batched
//          4-wide so the compiler can overlap the memory latency.
// Phase 2: all MFMAs, accumulators stay in registers.
// Phase 3: two half passes (ot = 0,1): deposit 16x496 f32 into the SAME LDS
//          (union with xn), then coalesced dwordx4 stores of 496-f32 runs.
// LDS = 33,024 B -> 4 blocks/CU (was 63,488 -> 2); VGPR capped at 128 via
// __launch_bounds__(256,4): acc = 64 VGPR, phase-1 batch peak ~50.
// ---------------------------------------------------------------------------
__global__ __launch_bounds__(256, 4) void main_kernel(
    const float* __restrict__ x,
    const float* __restrict__ sA, const float* __restrict__ sB,
    const unsigned short* __restrict__ wf,
    const float* __restrict__ fc_b,
    float* __restrict__ out) {
  const int q = blockIdx.x;   // 0..3  (o-quarter)
  const int tc = blockIdx.y;  // 0..62
  const int b = blockIdx.z;   // 0..15
  const int t0 = tc * 16;
  const int tid = threadIdx.x;

  __shared__ __align__(16) unsigned char lds_raw[16 * 1032 * 2];  // 33,024 B
  unsigned short(*xn)[1032] = (unsigned short(*)[1032])lds_raw;
  float(*stage)[496] = (float(*)[496])lds_raw;  // 16*496*4 = 31,744 B

  // zero xn (pads must be 0 so MFMA K-padding contributes nothing)
  for (int e = tid; e < 2064; e += 256)
    ((uint4*)lds_raw)[e] = make_uint4(0u, 0u, 0u, 0u);
  __syncthreads();

  // Phase 1: x (f32) -> normalized bf16, layout [t_local][kp].
  // d = tid + j*256, j = 0..15 uniform + 16-thread tail (f = 256).
  // Loads batched 4-wide: addresses are pure functions of tid, so each batch
  // issues 12 independent loads before any use -> 1 latency per batch, not 4.
  const float2* xrow = (const float2*)x + (long)b * 257 * 1000 + t0;
  const float* sAb = sA + (b << 10);
  const float* sBb = sB + (b << 10);
#pragma unroll
  for (int batch = 0; batch < 4; ++batch) {
    float2 xv[4], av[4], sv[4];
    int ks[4], kps[4];
    bool val[4];
#pragma unroll
    for (int j = 0; j < 4; ++j) {
      int d = tid + (batch * 4 + j) * 256;  // < 4096
      int f = d >> 4;
      int k = d & 15;
      int i = band_of_f(f);
      int kp = (i << 5) + 2 * (f - f0_of_band(i));
      bool v = (t0 + k < 1000);
      ks[j] = k; kps[j] = kp; val[j] = v;
      if (v) {
        xv[j] = xrow[(long)f * 1000 + k];
        av[j] = *(const float2*)(sAb + kp);
        sv[j] = *(const float2*)(sBb + kp);
      }
    }
#pragma unroll
    for (int j = 0; j < 4; ++j) {
      if (val[j]) {
        unsigned int r0 = f2bf(xv[j].x * av[j].x + sv[j].x);
        unsigned int r1 = f2bf(xv[j].y * av[j].y + sv[j].y);
        *(unsigned int*)&xn[ks[j]][kps[j]] = r0 | (r1 << 16);  // kp even
      }
    }
  }
  // tail: d = 4096..4111 -> f = 256 (band 30, cidx 32/33 -> kp 992)
  if (tid < 16 && t0 + tid < 1000) {
    float2 v = xrow[(long)256 * 1000 + tid];
    float2 av = *(const float2*)(sAb + 992);
    float2 sv = *(const float2*)(sBb + 992);
    unsigned int r0 = f2bf(v.x * av.x + sv.x);
    unsigned int r1 = f2bf(v.y * av.y + sv.y);
    *(unsigned int*)&xn[tid][992] = r0 | (r1 << 16);
  }
  __syncthreads();

  // Phase 2: MFMAs; wave wv handles bands wv, wv+4, ... (acc in registers)
  const int wv = tid >> 6;
  const int l = tid & 63;
  const int quad = l >> 4;
  const int n = l & 15;
  floatx4 acc[8][2];
#pragma unroll
  for (int it = 0; it < 8; ++it) {
    const int band = wv + it * 4;
    if (band >= 31) break;
    const bool dbl = (band == 30);  // c=34 -> second kstep
    short8 a0 = *(const short8*)&xn[n][(band << 5) + (quad << 3)];
#pragma unroll
    for (int ot = 0; ot < 2; ++ot) {
      const int OT = (q << 1) | ot;
      const int o = OT * 16 + n;
      float bias = fc_b[band * 128 + o];
      floatx4 a = {bias, bias, bias, bias};
      short8 b0 = ((const short8*)wf)[(band * 8 + OT) * 64 + l];
      a = __builtin_amdgcn_mfma_f32_16x16x32_bf16(a0, b0, a, 0, 0, 0);
      if (dbl) {
        short8 a1 = *(const short8*)&xn[n][992 + (quad << 3)];
        short8 b1 = ((const short8*)wf)[(31 * 8 + OT) * 64 + l];
        a = __builtin_amdgcn_mfma_f32_16x16x32_bf16(a1, b1, a, 0, 0, 0);
      }
      acc[it][ot] = a;
    }
  }
  __syncthreads();  // all xn reads done; safe to overwrite union

  // Phase 3: two half passes over ot. Each pass deposits D fragments into
  // stage[m][n*31 + band] (m = quad*4 + r; D row(m)=quad*4+r, col=lane&15,
  // m89/m91-verified) then stores 16 rows x 496 f32, contiguous in out at
  // (b*1000+t)*3968 + q*992 + ot*496 (uint4-aligned, 64B-aligned rows).
#pragma unroll
  for (int ot = 0; ot < 2; ++ot) {
    if (ot) __syncthreads();  // pass-0 store reads done before overwrite
#pragma unroll
    for (int it = 0; it < 8; ++it) {
      const int band = wv + it * 4;
      if (band >= 31) break;
#pragma unroll
      for (int r = 0; r < 4; ++r)
        stage[(quad << 2) + r][n * 31 + band] = acc[it][ot][r];
    }
    __syncthreads();
    for (int e = tid; e < 16 * 124; e += 256) {
      int m = e / 124;
      int d = e - m * 124;
      int t = t0 + m;
      if (t < 1000) {
        uint4 v = ((const uint4*)&stage[m][0])[d];
        ((uint4*)out)[(long)(b * 1000 + t) * 992 + q * 248 + ot * 124 + d] = v;
      }
    }
  }
}

extern "C" void kernel_launch(void* const* d_in, const int* in_sizes, int n_in,
                              void* d_out, int out_size, void* d_ws, size_t ws_size,
                              hipStream_t stream) {
  const float* x = (const float*)d_in[0];
  const float* gn_w = (const float*)d_in[1];
  const float* gn_b = (const float*)d_in[2];
  const float* fc_w = (const float*)d_in[3];
  const float* fc_b = (const float*)d_in[4];
  float* out = (float*)d_out;

  float* sA = (float*)d_ws;
  float* sB = sA + 16 * 1024;
  unsigned short* wf = (unsigned short*)(sB + 16 * 1024);

  prep_kernel<<<560, 256, 0, stream>>>(x, gn_w, gn_b, fc_w, sA, sB, wf);
  main_kernel<<<dim3(4, 63, 16), 256, 0, stream>>>(x, sA, sB, wf, fc_b, out);
}

// Round 2
// 334.118 us; speedup vs baseline: 1.1658x; 1.0105x over previous
//
#include <hip/hip_runtime.h>
#include <hip/hip_bf16.h>

// BandSplit on MI355X — round 3.
// R2 post-mortem: dur 389.5 -> 337.6 (predicted 350-365). Our kernels still
// below the top-5 cutoff (<164 us). Two accounting models fit: (a) 2 poison
// fills/iter (~315 us) + ours ~25 us => near harness floor; (b) 1 fill + ours
// ~170 us. This round targets (b)'s only identified waste — q-siblings on
// different XCDs re-fetching the same 32 KB x-slice 4x — by padding tc to 64
// and making tc the fastest grid dim (siblings differ by 64 = 0 mod 8 =>
// same XCD => x/wf L2-hot). Plus fc_b bias preload under phase-1 latency.
//
// ws layout (f32 unless noted):
//   sA : float[16][1024]    rsigma*gn_w at K-padded positions (band i -> kp=32i)
//   sB : float[16][1024]    gn_b - mu*rsigma*gn_w
//   wf : ushort[32*8*64*8]  fc_w as bf16 in MFMA B-fragment order, zero padded
// total 393,216 B (unchanged).

typedef short short8 __attribute__((ext_vector_type(8)));
typedef float floatx4 __attribute__((ext_vector_type(4)));

__device__ __forceinline__ unsigned short f2bf(float f) {
  unsigned int u = __float_as_uint(f);
  u = (u + 0x7fffu + ((u >> 16) & 1u)) >> 16;  // RNE
  return (unsigned short)u;
}

// BANDS = [2, 3x10, 8x12, 16x7, 17]; c = 2*band; K padded to 32 per band
// (band 30: c=34 -> ksteps 30 and 31).
__device__ __forceinline__ int band_of_f(int f) {
  if (f < 2) return 0;
  if (f < 32) return 1 + (f - 2) / 3;
  if (f < 128) return 11 + (f - 32) / 8;
  if (f < 240) return 23 + (f - 128) / 16;
  return 30;
}
__device__ __forceinline__ int f0_of_band(int i) {
  if (i == 0) return 0;
  if (i <= 10) return 2 + 3 * (i - 1);
  if (i <= 22) return 32 + 8 * (i - 11);
  if (i <= 29) return 128 + 16 * (i - 23);
  return 240;
}
__device__ __forceinline__ int c_of_band(int i) {
  if (i == 0) return 4;
  if (i <= 10) return 6;
  if (i <= 22) return 16;
  if (i <= 29) return 32;
  return 34;
}
__device__ __forceinline__ int bw_of_band(int i) {
  if (i == 0) return 2;
  if (i <= 10) return 3;
  if (i <= 22) return 8;
  if (i <= 29) return 16;
  return 17;
}

// ---------------------------------------------------------------------------
// Kernel 1 (fused): blocks 0..495 = per-(band,batch) GroupNorm stats folded
// into per-channel affine sA/sB; blocks 496..559 = fc_w (f32) -> bf16 MFMA
// B-fragment order. Independent work, one launch.
// ---------------------------------------------------------------------------
__global__ __launch_bounds__(256) void prep_kernel(
    const float* __restrict__ x,
    const float* __restrict__ gn_w,
    const float* __restrict__ gn_b,
    const float* __restrict__ fc_w,
    float* __restrict__ sA, float* __restrict__ sB,
    unsigned short* __restrict__ wf) {
  const int blk = blockIdx.x;
  const int tid = threadIdx.x;
  __shared__ float redS[4], redQ[4];
  __shared__ float musig[2];

  if (blk >= 496) {
    // ---- wprep part: flat short8 index gid = ks*512 + ot*64 + lane;
    // element j = Wp[kp = ks*32 + (lane>>4)*8 + j][o = ot*16 + (lane&15)].
    const int gid = (blk - 496) * 256 + tid;  // 0..16383
    const int ks = gid >> 9;
    const int rem = gid & 511;
    const int ot = rem >> 6;
    const int l = rem & 63;
    const int o = ot * 16 + (l & 15);
    const int kbase = ks * 32 + ((l >> 4) << 3);
    short8 v;
#pragma unroll
    for (int j = 0; j < 8; ++j) {
      int kp = kbase + j;
      int i = (kp >= 960) ? 30 : (kp >> 5);
      int cidx = kp - (i << 5);
      int c = c_of_band(i);
      unsigned short w =
          (cidx < c) ? f2bf(fc_w[(i * 128 + o) * 34 + cidx]) : (unsigned short)0;
      v[j] = (short)w;
    }
    ((short8*)wf)[gid] = v;
    return;
  }

  // ---- stats part
  const int i = blk % 31;  // band
  const int b = blk / 31;  // batch
  const int bw = bw_of_band(i);
  const int f0 = f0_of_band(i);
  // slab: x[b, f0:f0+bw, :, :] -> contiguous bw*2000 f32; start*4 % 16 == 0
  const long start = ((long)(b * 257 + f0)) * 2000;
  const float4* p4 = (const float4*)(x + start);
  const int nchunk = bw * 500;  // 4 f32 per chunk

  float s = 0.f, sq = 0.f;
  for (int e = tid; e < nchunk; e += 256) {
    float4 v = p4[e];
    s += v.x + v.y + v.z + v.w;
    sq += v.x * v.x + v.y * v.y + v.z * v.z + v.w * v.w;
  }
#pragma unroll
  for (int off = 32; off > 0; off >>= 1) {
    s += __shfl_down(s, off);
    sq += __shfl_down(sq, off);
  }
  if ((tid & 63) == 0) { redS[tid >> 6] = s; redQ[tid >> 6] = sq; }
  __syncthreads();
  if (tid == 0) {
    float S = redS[0] + redS[1] + redS[2] + redS[3];
    float Q = redQ[0] + redQ[1] + redQ[2] + redQ[3];
    float cnt = (float)(bw * 2000);
    float mu = S / cnt;
    float var = Q / cnt - mu * mu;
    musig[0] = mu;
    musig[1] = rsqrtf(var + 1e-5f);
  }
  __syncthreads();
  const int c = c_of_band(i);
  if (tid < c) {
    float mu = musig[0], rs = musig[1];
    float gw = gn_w[i * 34 + tid];
    float gb = gn_b[i * 34 + tid];
    float a = rs * gw;
    int kp = i * 32 + tid;  // band 30 spills into kstep 31
    sA[(b << 10) + kp] = a;
    sB[(b << 10) + kp] = gb - mu * a;
  }
}

// ---------------------------------------------------------------------------
// Kernel 2: main. Grid = (tc 64 [63 + 1 pad], q 4, b 16); tc is the FASTEST
// dim so the 4 q-siblings of an (tc,b) pair differ by 64 in linear block id
// => 64 % 8 == 0 => same XCD under round-robin => the shared 32 KB x-slice
// and the 512 KB wf table are XCD-L2 hits instead of 4x HBM/L3 refetch.
// Phase 1: stage normalized bf16 xn in A-fragment layout (LDS), loads batched
//          4-wide; fc_b biases preloaded to regs under the same latency.
// Phase 2: all MFMAs, accumulators stay in registers.
// Phase 3: two half passes (ot = 0,1): deposit 16x496 f32 into the SAME LDS
//          (union with xn), then coalesced dwordx4 stores of 496-f32 runs.
// LDS = 33,024 B -> 4 blocks/CU with __launch_bounds__(256,4).
// ---------------------------------------------------------------------------
__global__ __launch_bounds__(256, 4) void main_kernel(
    const float* __restrict__ x,
    const float* __restrict__ sA, const float* __restrict__ sB,
    const unsigned short* __restrict__ wf,
    const float* __restrict__ fc_b,
    float* __restrict__ out) {
  const int tc = blockIdx.x;  // 0..63 (63 is grid pad)
  const int q = blockIdx.y;   // 0..3  (o-quarter)
  const int b = blockIdx.z;   // 0..15
  const int t0 = tc * 16;
  if (t0 >= 1000) return;  // uniform pad-block exit, before any barrier
  const int tid = threadIdx.x;

  __shared__ __align__(16) unsigned char lds_raw[16 * 1032 * 2];  // 33,024 B
  unsigned short(*xn)[1032] = (unsigned short(*)[1032])lds_raw;
  float(*stage)[496] = (float(*)[496])lds_raw;  // 16*496*4 = 31,744 B

  const int wv = tid >> 6;
  const int l = tid & 63;
  const int quad = l >> 4;
  const int n = l & 15;

  // fc_b bias preload: 16 independent 4B loads, issued before phase-1 so
  // their latency hides under the x-load round-trips. Static indexing only.
  float bias[8][2];
#pragma unroll
  for (int it = 0; it < 8; ++it) {
    const int band = wv + it * 4;
    if (band >= 31) break;
#pragma unroll
    for (int ot = 0; ot < 2; ++ot)
      bias[it][ot] = fc_b[band * 128 + (((q << 1) | ot) << 4) + n];
  }

  // zero xn (pads must be 0 so MFMA K-padding contributes nothing)
  for (int e = tid; e < 2064; e += 256)
    ((uint4*)lds_raw)[e] = make_uint4(0u, 0u, 0u, 0u);
  __syncthreads();

  // Phase 1: x (f32) -> normalized bf16, layout [t_local][kp].
  // d = tid + j*256, j = 0..15 uniform + 16-thread tail (f = 256).
  // Loads batched 4-wide: addresses are pure functions of tid, so each batch
  // issues 12 independent loads before any use -> 1 latency per batch, not 4.
  const float2* xrow = (const float2*)x + (long)b * 257 * 1000 + t0;
  const float* sAb = sA + (b << 10);
  const float* sBb = sB + (b << 10);
#pragma unroll
  for (int batch = 0; batch < 4; ++batch) {
    float2 xv[4], av[4], sv[4];
    int ks[4], kps[4];
    bool val[4];
#pragma unroll
    for (int j = 0; j < 4; ++j) {
      int d = tid + (batch * 4 + j) * 256;  // < 4096
      int f = d >> 4;
      int k = d & 15;
      int i = band_of_f(f);
      int kp = (i << 5) + 2 * (f - f0_of_band(i));
      bool v = (t0 + k < 1000);
      ks[j] = k; kps[j] = kp; val[j] = v;
      if (v) {
        xv[j] = xrow[(long)f * 1000 + k];
        av[j] = *(const float2*)(sAb + kp);
        sv[j] = *(const float2*)(sBb + kp);
      }
    }
#pragma unroll
    for (int j = 0; j < 4; ++j) {
      if (val[j]) {
        unsigned int r0 = f2bf(xv[j].x * av[j].x + sv[j].x);
        unsigned int r1 = f2bf(xv[j].y * av[j].y + sv[j].y);
        *(unsigned int*)&xn[ks[j]][kps[j]] = r0 | (r1 << 16);  // kp even
      }
    }
  }
  // tail: d = 4096..4111 -> f = 256 (band 30, cidx 32/33 -> kp 992)
  if (tid < 16 && t0 + tid < 1000) {
    float2 v = xrow[(long)256 * 1000 + tid];
    float2 av = *(const float2*)(sAb + 992);
    float2 sv = *(const float2*)(sBb + 992);
    unsigned int r0 = f2bf(v.x * av.x + sv.x);
    unsigned int r1 = f2bf(v.y * av.y + sv.y);
    *(unsigned int*)&xn[tid][992] = r0 | (r1 << 16);
  }
  __syncthreads();

  // Phase 2: MFMAs; wave wv handles bands wv, wv+4, ... (acc in registers)
  floatx4 acc[8][2];
#pragma unroll
  for (int it = 0; it < 8; ++it) {
    const int band = wv + it * 4;
    if (band >= 31) break;
    const bool dbl = (band == 30);  // c=34 -> second kstep
    short8 a0 = *(const short8*)&xn[n][(band << 5) + (quad << 3)];
#pragma unroll
    for (int ot = 0; ot < 2; ++ot) {
      const int OT = (q << 1) | ot;
      float bv = bias[it][ot];
      floatx4 a = {bv, bv, bv, bv};
      short8 b0 = ((const short8*)wf)[(band * 8 + OT) * 64 + l];
      a = __builtin_amdgcn_mfma_f32_16x16x32_bf16(a0, b0, a, 0, 0, 0);
      if (dbl) {
        short8 a1 = *(const short8*)&xn[n][992 + (quad << 3)];
        short8 b1 = ((const short8*)wf)[(31 * 8 + OT) * 64 + l];
        a = __builtin_amdgcn_mfma_f32_16x16x32_bf16(a1, b1, a, 0, 0, 0);
      }
      acc[it][ot] = a;
    }
  }
  __syncthreads();  // all xn reads done; safe to overwrite union

  // Phase 3: two half passes over ot. Each pass deposits D fragments into
  // stage[m][n*31 + band] (m = quad*4 + r; D row(m)=quad*4+r, col=lane&15,
  // m89/m91-verified) then stores 16 rows x 496 f32, contiguous in out at
  // (b*1000+t)*3968 + q*992 + ot*496 (uint4-aligned, 64B-aligned rows).
#pragma unroll
  for (int ot = 0; ot < 2; ++ot) {
    if (ot) __syncthreads();  // pass-0 store reads done before overwrite
#pragma unroll
    for (int it = 0; it < 8; ++it) {
      const int band = wv + it * 4;
      if (band >= 31) break;
#pragma unroll
      for (int r = 0; r < 4; ++r)
        stage[(quad << 2) + r][n * 31 + band] = acc[it][ot][r];
    }
    __syncthreads();
    for (int e = tid; e < 16 * 124; e += 256) {
      int m = e / 124;
      int d = e - m * 124;
      int t = t0 + m;
      if (t < 1000) {
        uint4 v = ((const uint4*)&stage[m][0])[d];
        ((uint4*)out)[(long)(b * 1000 + t) * 992 + q * 248 + ot * 124 + d] = v;
      }
    }
  }
}

extern "C" void kernel_launch(void* const* d_in, const int* in_sizes, int n_in,
                              void* d_out, int out_size, void* d_ws, size_t ws_size,
                              hipStream_t stream) {
  const float* x = (const float*)d_in[0];
  const float* gn_w = (const float*)d_in[1];
  const float* gn_b = (const float*)d_in[2];
  const float* fc_w = (const float*)d_in[3];
  const float* fc_b = (const float*)d_in[4];
  float* out = (float*)d_out;

  float* sA = (float*)d_ws;
  float* sB = sA + 16 * 1024;
  unsigned short* wf = (unsigned short*)(sB + 16 * 1024);

  prep_kernel<<<560, 256, 0, stream>>>(x, gn_w, gn_b, fc_w, sA, sB, wf);
  main_kernel<<<dim3(64, 4, 16), 256, 0, stream>>>(x, sA, sB, wf, fc_b, out);
}

// Round 3
// 317.437 us; speedup vs baseline: 1.2271x; 1.0526x over previous
//
#include <hip/hip_runtime.h>
#include <hip/hip_bf16.h>

// BandSplit on MI355X — round 4.
// R3 post-mortem: XCD swizzle = noise (+3.5us). Accounting: 2-fill model is
// arithmetically impossible (would leave 6us for kernels with a 50us floor),
// so graph = 1 big fill (~163us) + reset memsets + prep + main (~170us
// combined). Main's excess over its ~50us memory floor is phase-1 load
// count: 51 vmem ops/thread, 2/3 redundant sA/sB re-reads. This round:
// float4 x loads (2 t per load, halves x AND sA/sB ops -> ~27/thread,
// bit-identical math) + 4-wide unrolled stats loads.
//
// ws layout (f32 unless noted):
//   sA : float[16][1024]    rsigma*gn_w at K-padded positions (band i -> kp=32i)
//   sB : float[16][1024]    gn_b - mu*rsigma*gn_w
//   wf : ushort[32*8*64*8]  fc_w as bf16 in MFMA B-fragment order, zero padded
// total 393,216 B (unchanged).

typedef short short8 __attribute__((ext_vector_type(8)));
typedef float floatx4 __attribute__((ext_vector_type(4)));

__device__ __forceinline__ unsigned short f2bf(float f) {
  unsigned int u = __float_as_uint(f);
  u = (u + 0x7fffu + ((u >> 16) & 1u)) >> 16;  // RNE
  return (unsigned short)u;
}

// BANDS = [2, 3x10, 8x12, 16x7, 17]; c = 2*band; K padded to 32 per band
// (band 30: c=34 -> ksteps 30 and 31).
__device__ __forceinline__ int band_of_f(int f) {
  if (f < 2) return 0;
  if (f < 32) return 1 + (f - 2) / 3;
  if (f < 128) return 11 + (f - 32) / 8;
  if (f < 240) return 23 + (f - 128) / 16;
  return 30;
}
__device__ __forceinline__ int f0_of_band(int i) {
  if (i == 0) return 0;
  if (i <= 10) return 2 + 3 * (i - 1);
  if (i <= 22) return 32 + 8 * (i - 11);
  if (i <= 29) return 128 + 16 * (i - 23);
  return 240;
}
__device__ __forceinline__ int c_of_band(int i) {
  if (i == 0) return 4;
  if (i <= 10) return 6;
  if (i <= 22) return 16;
  if (i <= 29) return 32;
  return 34;
}
__device__ __forceinline__ int bw_of_band(int i) {
  if (i == 0) return 2;
  if (i <= 10) return 3;
  if (i <= 22) return 8;
  if (i <= 29) return 16;
  return 17;
}

// ---------------------------------------------------------------------------
// Kernel 1 (fused): blocks 0..495 = per-(band,batch) GroupNorm stats folded
// into per-channel affine sA/sB; blocks 496..559 = fc_w (f32) -> bf16 MFMA
// B-fragment order. Independent work, one launch.
// ---------------------------------------------------------------------------
__global__ __launch_bounds__(256) void prep_kernel(
    const float* __restrict__ x,
    const float* __restrict__ gn_w,
    const float* __restrict__ gn_b,
    const float* __restrict__ fc_w,
    float* __restrict__ sA, float* __restrict__ sB,
    unsigned short* __restrict__ wf) {
  const int blk = blockIdx.x;
  const int tid = threadIdx.x;
  __shared__ float redS[4], redQ[4];
  __shared__ float musig[2];

  if (blk >= 496) {
    // ---- wprep part: flat short8 index gid = ks*512 + ot*64 + lane;
    // element j = Wp[kp = ks*32 + (lane>>4)*8 + j][o = ot*16 + (lane&15)].
    const int gid = (blk - 496) * 256 + tid;  // 0..16383
    const int ks = gid >> 9;
    const int rem = gid & 511;
    const int ot = rem >> 6;
    const int l = rem & 63;
    const int o = ot * 16 + (l & 15);
    const int kbase = ks * 32 + ((l >> 4) << 3);
    short8 v;
#pragma unroll
    for (int j = 0; j < 8; ++j) {
      int kp = kbase + j;
      int i = (kp >= 960) ? 30 : (kp >> 5);
      int cidx = kp - (i << 5);
      int c = c_of_band(i);
      unsigned short w =
          (cidx < c) ? f2bf(fc_w[(i * 128 + o) * 34 + cidx]) : (unsigned short)0;
      v[j] = (short)w;
    }
    ((short8*)wf)[gid] = v;
    return;
  }

  // ---- stats part
  const int i = blk % 31;  // band
  const int b = blk / 31;  // batch
  const int bw = bw_of_band(i);
  const int f0 = f0_of_band(i);
  // slab: x[b, f0:f0+bw, :, :] -> contiguous bw*2000 f32; start*4 % 16 == 0
  const long start = ((long)(b * 257 + f0)) * 2000;
  const float4* p4 = (const float4*)(x + start);
  const int nchunk = bw * 500;  // 4 f32 per chunk

  // 4-wide batched loads: break the serial load->accumulate round-trips
  // (band-30 blocks issue 34 loads; batching overlaps their latency).
  float s = 0.f, sq = 0.f;
  int e = tid;
  for (; e + 768 < nchunk; e += 1024) {
    float4 w0 = p4[e];
    float4 w1 = p4[e + 256];
    float4 w2 = p4[e + 512];
    float4 w3 = p4[e + 768];
    s += (w0.x + w0.y + w0.z + w0.w) + (w1.x + w1.y + w1.z + w1.w) +
         (w2.x + w2.y + w2.z + w2.w) + (w3.x + w3.y + w3.z + w3.w);
    sq += (w0.x * w0.x + w0.y * w0.y + w0.z * w0.z + w0.w * w0.w) +
          (w1.x * w1.x + w1.y * w1.y + w1.z * w1.z + w1.w * w1.w) +
          (w2.x * w2.x + w2.y * w2.y + w2.z * w2.z + w2.w * w2.w) +
          (w3.x * w3.x + w3.y * w3.y + w3.z * w3.z + w3.w * w3.w);
  }
  for (; e < nchunk; e += 256) {
    float4 v = p4[e];
    s += v.x + v.y + v.z + v.w;
    sq += v.x * v.x + v.y * v.y + v.z * v.z + v.w * v.w;
  }
#pragma unroll
  for (int off = 32; off > 0; off >>= 1) {
    s += __shfl_down(s, off);
    sq += __shfl_down(sq, off);
  }
  if ((tid & 63) == 0) { redS[tid >> 6] = s; redQ[tid >> 6] = sq; }
  __syncthreads();
  if (tid == 0) {
    float S = redS[0] + redS[1] + redS[2] + redS[3];
    float Q = redQ[0] + redQ[1] + redQ[2] + redQ[3];
    float cnt = (float)(bw * 2000);
    float mu = S / cnt;
    float var = Q / cnt - mu * mu;
    musig[0] = mu;
    musig[1] = rsqrtf(var + 1e-5f);
  }
  __syncthreads();
  const int c = c_of_band(i);
  if (tid < c) {
    float mu = musig[0], rs = musig[1];
    float gw = gn_w[i * 34 + tid];
    float gb = gn_b[i * 34 + tid];
    float a = rs * gw;
    int kp = i * 32 + tid;  // band 30 spills into kstep 31
    sA[(b << 10) + kp] = a;
    sB[(b << 10) + kp] = gb - mu * a;
  }
}

// ---------------------------------------------------------------------------
// Kernel 2: main. Grid = (tc 64 [63 + 1 pad], q 4, b 16); tc fastest so the
// 4 q-siblings of a (tc,b) pair differ by 64 = 0 mod 8 in linear id => same
// XCD => shared x-slice / wf are L2 hits.
// Phase 1: float4 x loads (2 adjacent t per load; t0 even + 2*kpair even =>
//          a valid load never straddles t=999). One sA/sB float2 pair serves
//          both t. ~27 vmem ops/thread (was 51). Math bit-identical.
// Phase 2: all MFMAs, accumulators stay in registers.
// Phase 3: two half passes (ot = 0,1): deposit 16x496 f32 into the SAME LDS
//          (union with xn), then coalesced dwordx4 stores of 496-f32 runs.
// LDS = 33,024 B -> 4 blocks/CU with __launch_bounds__(256,4).
// ---------------------------------------------------------------------------
__global__ __launch_bounds__(256, 4) void main_kernel(
    const float* __restrict__ x,
    const float* __restrict__ sA, const float* __restrict__ sB,
    const unsigned short* __restrict__ wf,
    const float* __restrict__ fc_b,
    float* __restrict__ out) {
  const int tc = blockIdx.x;  // 0..63 (63 is grid pad)
  const int q = blockIdx.y;   // 0..3  (o-quarter)
  const int b = blockIdx.z;   // 0..15
  const int t0 = tc * 16;
  if (t0 >= 1000) return;  // uniform pad-block exit, before any barrier
  const int tid = threadIdx.x;

  __shared__ __align__(16) unsigned char lds_raw[16 * 1032 * 2];  // 33,024 B
  unsigned short(*xn)[1032] = (unsigned short(*)[1032])lds_raw;
  float(*stage)[496] = (float(*)[496])lds_raw;  // 16*496*4 = 31,744 B

  const int wv = tid >> 6;
  const int l = tid & 63;
  const int quad = l >> 4;
  const int n = l & 15;

  // fc_b bias preload: 16 independent 4B loads, issued before phase-1 so
  // their latency hides under the x-load round-trips. Static indexing only.
  float bias[8][2];
#pragma unroll
  for (int it = 0; it < 8; ++it) {
    const int band = wv + it * 4;
    if (band >= 31) break;
#pragma unroll
    for (int ot = 0; ot < 2; ++ot)
      bias[it][ot] = fc_b[band * 128 + (((q << 1) | ot) << 4) + n];
  }

  // zero xn (pads must be 0 so MFMA K-padding contributes nothing)
  for (int e = tid; e < 2064; e += 256)
    ((uint4*)lds_raw)[e] = make_uint4(0u, 0u, 0u, 0u);
  __syncthreads();

  // Phase 1: x (f32) -> normalized bf16, layout [t_local][kp].
  // float4 element d = 0..2047: f = d>>3, kpair = d&7 -> t = t0 + 2*kpair,
  // covers t and t+1 (both < 1000 whenever t < 1000, since t is even).
  // 4-wide batches: 12 independent loads issued per batch before any use.
  const float4* xq = (const float4*)(x + (long)b * 514000 + (long)t0 * 2);
  const float* sAb = sA + (b << 10);
  const float* sBb = sB + (b << 10);
#pragma unroll
  for (int half = 0; half < 2; ++half) {
    float4 xv[4];
    float2 av[4], sv[4];
    int row[4], kps[4];
    bool val[4];
#pragma unroll
    for (int j = 0; j < 4; ++j) {
      int d = tid + (half * 4 + j) * 256;  // 0..2047
      int f = d >> 3;
      int kpair = d & 7;
      int i = band_of_f(f);
      int kp = (i << 5) + 2 * (f - f0_of_band(i));
      bool v = (t0 + 2 * kpair < 1000);
      row[j] = 2 * kpair; kps[j] = kp; val[j] = v;
      if (v) {
        xv[j] = xq[f * 500 + kpair];
        av[j] = *(const float2*)(sAb + kp);
        sv[j] = *(const float2*)(sBb + kp);
      }
    }
#pragma unroll
    for (int j = 0; j < 4; ++j) {
      if (val[j]) {
        unsigned int r0 = f2bf(xv[j].x * av[j].x + sv[j].x);
        unsigned int r1 = f2bf(xv[j].y * av[j].y + sv[j].y);
        unsigned int r2 = f2bf(xv[j].z * av[j].x + sv[j].x);
        unsigned int r3 = f2bf(xv[j].w * av[j].y + sv[j].y);
        *(unsigned int*)&xn[row[j]][kps[j]] = r0 | (r1 << 16);      // kp even
        *(unsigned int*)&xn[row[j] + 1][kps[j]] = r2 | (r3 << 16);
      }
    }
  }
  // tail: f = 256 (band 30, cidx 32/33 -> kp 992), 8 float4 by tid<8
  if (tid < 8 && t0 + 2 * tid < 1000) {
    float4 v = xq[256 * 500 + tid];
    float2 av = *(const float2*)(sAb + 992);
    float2 sv = *(const float2*)(sBb + 992);
    unsigned int r0 = f2bf(v.x * av.x + sv.x);
    unsigned int r1 = f2bf(v.y * av.y + sv.y);
    unsigned int r2 = f2bf(v.z * av.x + sv.x);
    unsigned int r3 = f2bf(v.w * av.y + sv.y);
    *(unsigned int*)&xn[2 * tid][992] = r0 | (r1 << 16);
    *(unsigned int*)&xn[2 * tid + 1][992] = r2 | (r3 << 16);
  }
  __syncthreads();

  // Phase 2: MFMAs; wave wv handles bands wv, wv+4, ... (acc in registers)
  floatx4 acc[8][2];
#pragma unroll
  for (int it = 0; it < 8; ++it) {
    const int band = wv + it * 4;
    if (band >= 31) break;
    const bool dbl = (band == 30);  // c=34 -> second kstep
    short8 a0 = *(const short8*)&xn[n][(band << 5) + (quad << 3)];
#pragma unroll
    for (int ot = 0; ot < 2; ++ot) {
      const int OT = (q << 1) | ot;
      float bv = bias[it][ot];
      floatx4 a = {bv, bv, bv, bv};
      short8 b0 = ((const short8*)wf)[(band * 8 + OT) * 64 + l];
      a = __builtin_amdgcn_mfma_f32_16x16x32_bf16(a0, b0, a, 0, 0, 0);
      if (dbl) {
        short8 a1 = *(const short8*)&xn[n][992 + (quad << 3)];
        short8 b1 = ((const short8*)wf)[(31 * 8 + OT) * 64 + l];
        a = __builtin_amdgcn_mfma_f32_16x16x32_bf16(a1, b1, a, 0, 0, 0);
      }
      acc[it][ot] = a;
    }
  }
  __syncthreads();  // all xn reads done; safe to overwrite union

  // Phase 3: two half passes over ot. Each pass deposits D fragments into
  // stage[m][n*31 + band] (m = quad*4 + r; D row(m)=quad*4+r, col=lane&15,
  // m89/m91-verified) then stores 16 rows x 496 f32, contiguous in out at
  // (b*1000+t)*3968 + q*992 + ot*496 (uint4-aligned, 64B-aligned rows).
#pragma unroll
  for (int ot = 0; ot < 2; ++ot) {
    if (ot) __syncthreads();  // pass-0 store reads done before overwrite
#pragma unroll
    for (int it = 0; it < 8; ++it) {
      const int band = wv + it * 4;
      if (band >= 31) break;
#pragma unroll
      for (int r = 0; r < 4; ++r)
        stage[(quad << 2) + r][n * 31 + band] = acc[it][ot][r];
    }
    __syncthreads();
    for (int e = tid; e < 16 * 124; e += 256) {
      int m = e / 124;
      int d = e - m * 124;
      int t = t0 + m;
      if (t < 1000) {
        uint4 v = ((const uint4*)&stage[m][0])[d];
        ((uint4*)out)[(long)(b * 1000 + t) * 992 + q * 248 + ot * 124 + d] = v;
      }
    }
  }
}

extern "C" void kernel_launch(void* const* d_in, const int* in_sizes, int n_in,
                              void* d_out, int out_size, void* d_ws, size_t ws_size,
                              hipStream_t stream) {
  const float* x = (const float*)d_in[0];
  const float* gn_w = (const float*)d_in[1];
  const float* gn_b = (const float*)d_in[2];
  const float* fc_w = (const float*)d_in[3];
  const float* fc_b = (const float*)d_in[4];
  float* out = (float*)d_out;

  float* sA = (float*)d_ws;
  float* sB = sA + 16 * 1024;
  unsigned short* wf = (unsigned short*)(sB + 16 * 1024);

  prep_kernel<<<560, 256, 0, stream>>>(x, gn_w, gn_b, fc_w, sA, sB, wf);
  main_kernel<<<dim3(64, 4, 16), 256, 0, stream>>>(x, sA, sB, wf, fc_b, out);
}